// Round 12
// baseline (68.965 us; speedup 1.0000x reference)
//
#include <hip/hip_runtime.h>
#include <cstddef>

#define Bn 16
#define Dn 512
#define Tn 2048
#define Ln 512
#define NLT 64      // l-tiles per b (Ln/8)
#define MAGIC 0x5EED5EEDu

// ---- K1 (merged): score (512) + align zero-fill (4096) + scan (16) ------
// score role release-stores a flag per 64-t chunk; scan role acquire-spins
// on its b's 32 flags then runs the full scan while fill blocks stream.
// Safe: scan waits only on score; nothing waits on scan (z is kernel 2).
__global__ __launch_bounds__(256) void scorefill_kernel(const float* __restrict__ x,
                                                        const float* __restrict__ w,
                                                        const int* __restrict__ xlen,
                                                        float* __restrict__ score,
                                                        float4* __restrict__ align4,
                                                        unsigned* __restrict__ flags,
                                                        float* __restrict__ norm,
                                                        float* __restrict__ loss_part,
                                                        float* __restrict__ zmask_out,
                                                        float* __restrict__ zlen_out,
                                                        int* __restrict__ wlo,
                                                        int* __restrict__ whi,
                                                        float* __restrict__ sMout,
                                                        float* __restrict__ sIout) {
    int bid = blockIdx.x;
    int tid = threadIdx.x;

    if (bid < 512) {                           // ================ score role
        int b   = bid >> 5;
        int tc  = bid & 31;
        int xl  = xlen[b];
        int t0c = tc * 64;
        if (t0c < xl) {
            int tq  = tid & 15;
            int dg  = tid >> 4;
            int t0  = t0c + tq * 4;
            const float* xb = x + (size_t)b * Dn * Tn + t0;
            float4 acc = make_float4(0.f, 0.f, 0.f, 0.f);
            int dbase = dg * 32;
#pragma unroll 8
            for (int i = 0; i < 32; ++i) {
                int d = dbase + i;
                float4 v = *(const float4*)&xb[(size_t)d * Tn];
                float wd = w[d];
                acc.x = fmaf(v.x, wd, acc.x);
                acc.y = fmaf(v.y, wd, acc.y);
                acc.z = fmaf(v.z, wd, acc.z);
                acc.w = fmaf(v.w, wd, acc.w);
            }
            __shared__ float4 red[16][16];
            red[dg][tq] = acc;
            __syncthreads();
            if (tid < 16) {
                float4 s = red[0][tid];
#pragma unroll
                for (int g = 1; g < 16; ++g) {
                    float4 r = red[g][tid];
                    s.x += r.x; s.y += r.y; s.z += r.z; s.w += r.w;
                }
                int t = t0c + tid * 4;
                float4 o;
                o.x = (t + 0 < xl) ? __expf(s.x) : 0.f;
                o.y = (t + 1 < xl) ? __expf(s.y) : 0.f;
                o.z = (t + 2 < xl) ? __expf(s.z) : 0.f;
                o.w = (t + 3 < xl) ? __expf(s.w) : 0.f;
                *(float4*)&score[b * Tn + t] = o;
            }
        } else {
            if (tid < 16)
                *(float4*)&score[b * Tn + t0c + tid * 4] = make_float4(0.f, 0.f, 0.f, 0.f);
        }
        __syncthreads();                       // all score writes done
        if (tid == 0)
            __hip_atomic_store(&flags[bid], MAGIC, __ATOMIC_RELEASE,
                               __HIP_MEMORY_SCOPE_AGENT);
        return;
    }

    if (bid < 512 + 4096) {                    // ================ fill role
        const size_t NT = (size_t)Bn * Ln * Tn / 16;
        size_t i = (size_t)(bid - 512) * 256 + tid;
        float4 z4 = make_float4(0.f, 0.f, 0.f, 0.f);
        align4[i]          = z4;
        align4[i + NT]     = z4;
        align4[i + 2 * NT] = z4;
        align4[i + 3 * NT] = z4;
        return;
    }

    // ======================================== scan role (16 blocks)
    int b = bid - (512 + 4096);
    if (tid < 32) {
        while (__hip_atomic_load(&flags[b * 32 + tid], __ATOMIC_ACQUIRE,
                                 __HIP_MEMORY_SCOPE_AGENT) != MAGIC) {}
    }
    __syncthreads();                           // score[b,:] visible

    int xl = xlen[b];
    int zl = (xl + 3) >> 2;
    const float* sc = score + b * Tn;

    __shared__ float sNorm[Tn];   // 8 KB
    __shared__ int   sTC[Ln];     // 2 KB

    float v[8]; float s = 0.f;
#pragma unroll
    for (int k = 0; k < 8; ++k) { v[k] = sc[tid * 8 + k]; s += v[k]; }

    float ps = s;
#pragma unroll
    for (int off = 1; off < 64; off <<= 1) {
        float n = __shfl_up(ps, off, 64);
        if ((tid & 63) >= off) ps += n;
    }
    __shared__ float wsum[4];
    if ((tid & 63) == 63) wsum[tid >> 6] = ps;
    __syncthreads();
    float base = 0.f;
#pragma unroll
    for (int wv = 0; wv < 4; ++wv) if (wv < (tid >> 6)) base += wsum[wv];
    float total = wsum[0] + wsum[1] + wsum[2] + wsum[3];
    float cum0  = sc[0];
    float scale = (float)(zl - 1) / (total - cum0);

    float run = base + ps - s;
    float nv[8];
#pragma unroll
    for (int k = 0; k < 8; ++k) {
        run += v[k];
        float xx = (run - cum0) * scale;
        nv[k] = xx;
        norm[b * Tn + tid * 8 + k] = xx;
        sNorm[tid * 8 + k] = xx;
    }

    float ls = 0.f;
#pragma unroll
    for (int k = 0; k < 8; ++k) {
        int t = tid * 8 + k;
        if (t >= 1 && t < xl) {
            float diff = v[k] * scale;
            ls += fmaxf(diff - 1.0f, 0.f);
        }
    }
#pragma unroll
    for (int off = 32; off; off >>= 1) ls += __shfl_down(ls, off, 64);
    __shared__ float lw[4];
    if ((tid & 63) == 0) lw[tid >> 6] = ls;

    for (int l = tid; l < Ln; l += 256)
        zmask_out[b * Ln + l] = (l * 4 < xl) ? 1.f : 0.f;
    if (tid == 0) zlen_out[b] = (float)zl;

    for (int i = tid; i < NLT; i += 256) {
        wlo[b * NLT + i] = xl;
        whi[b * NLT + i] = xl;
    }
    for (int l = tid; l < Ln; l += 256) sTC[l] = xl - 1;
    __syncthreads();
    if (tid == 0) loss_part[b] = (lw[0] + lw[1] + lw[2] + lw[3]) / (float)(xl - 1);

    // crossing detection (norm monotone non-decreasing => unique crossings)
#pragma unroll
    for (int k = 0; k < 8; ++k) {
        int t = tid * 8 + k;
        float vv = nv[k];
        float p  = (t == 0) ? -1e9f : sNorm[t - 1];
        int lsr = (int)floorf((p + 1.5f) * 0.125f) + 1; if (lsr < 0) lsr = 0;
        int ler = (int)floorf((vv + 1.5f) * 0.125f);    if (ler > NLT - 1) ler = NLT - 1;
        for (int lt = lsr; lt <= ler; ++lt) wlo[b * NLT + lt] = t;
        int hs = (int)ceilf((p - 8.5f) * 0.125f);       if (hs < 0) hs = 0;
        int he = (int)ceilf((vv - 8.5f) * 0.125f) - 1;  if (he > NLT - 1) he = NLT - 1;
        for (int lt = hs; lt <= he; ++lt) whi[b * NLT + lt] = t;
        int cs = (int)floorf(p) + 1;  if (cs < 0) cs = 0;
        int ce = (int)floorf(vv);     if (ce > Ln - 1) ce = Ln - 1;
        for (int l = cs; l <= ce; ++l) sTC[l] = t;
    }
    __syncthreads();

    // per-row exact max + truncated sum
    for (int l = tid; l < Ln; l += 256) {
        float mv = 0.f, iv = 0.f;
        if (l < zl) {
            int tc2 = sTC[l];
            float d1 = (float)l - sNorm[tc2];
            float m  = -5.f * d1 * d1;
            if (tc2 > 0) { float d0v = (float)l - sNorm[tc2 - 1]; float c = -5.f * d0v * d0v; m = fmaxf(m, c); }
            int lo = (l >= 2) ? sTC[l - 2] : 0;
            int hi = (l + 2 <= zl - 1) ? sTC[l + 2] : xl;
            int tcm1 = (tc2 > 0) ? tc2 - 1 : 0;
            if (lo > tcm1) lo = tcm1;
            int tcp1 = (tc2 + 1 < xl) ? tc2 + 1 : xl;
            if (hi < tcp1) hi = tcp1;
            float ssum = 0.f;
            for (int t = lo; t < hi; ++t) {
                float df = (float)l - sNorm[t];
                ssum += __expf(-5.f * df * df - m);
            }
            mv = m; iv = 1.f / ssum;
        }
        sMout[b * Ln + l] = mv;
        sIout[b * Ln + l] = iv;
    }

    // reset flags for the next call (any value != MAGIC works)
    if (tid < 32)
        __hip_atomic_store(&flags[b * 32 + tid], 0u, __ATOMIC_RELAXED,
                           __HIP_MEMORY_SCOPE_AGENT);
}

// -------- K2: z GEMM + alignment window writes + loss finalize -----------
__global__ __launch_bounds__(256) void z_kernel(const float* __restrict__ x,
                                                const float* __restrict__ norm,
                                                const int* __restrict__ xlen,
                                                const int* __restrict__ wlo,
                                                const int* __restrict__ whi,
                                                const float* __restrict__ sM,
                                                const float* __restrict__ sI,
                                                const float* __restrict__ loss_part,
                                                float* __restrict__ align,
                                                float* __restrict__ z,
                                                float* __restrict__ out_loss) {
    int tid = threadIdx.x;
    int bid = blockIdx.x;
    if (bid == 0 && tid == 0) {
        float s = 0.f;
        for (int i = 0; i < Bn; ++i) s += loss_part[i];
        out_loss[0] = s / (float)Bn;
    }
    int swz = (bid & 7) * 256 + (bid >> 3);   // bijective: 2048 = 8*256
    int b   = swz >> 7;
    int rem = swz & 127;
    int lt  = rem >> 1;
    int dh  = rem & 1;
    int l0  = lt * 8;
    int xl  = xlen[b];
    int zl  = (xl + 3) >> 2;
    int d   = dh * 256 + tid;
    size_t zr = (size_t)(b * Dn + d) * Ln + l0;

    if (l0 >= zl) {
        float4 z4 = make_float4(0.f, 0.f, 0.f, 0.f);
        *(float4*)&z[zr] = z4; *(float4*)&z[zr + 4] = z4;
        return;
    }

    int tlo = wlo[b * NLT + lt];
    int thi = whi[b * NLT + lt];
    if (thi > xl) thi = xl;
    int tA = tlo & ~15;                        // 64B-aligned window start

    __shared__ float sA[64][8];                // 2 KB, A[s][l]
    const float* nb = norm + b * Tn;
    const float* xr = x + (size_t)(b * Dn + d) * Tn;

    int al = tid >> 5;                         // A-build: l row 0..7
    int as = tid & 31;                         // A-build: slots as, as+32
    float ml = sM[b * Ln + l0 + al];
    float il = sI[b * Ln + l0 + al];
    float lr = (float)(l0 + al);
    float* ar = align + (size_t)(b * Ln + l0 + al) * Tn;

    float acc[8] = {};
    float4 rx[16];

    for (int t0 = tA; t0 < thi; t0 += 64) {    // normally ONE iteration
#pragma unroll
        for (int j = 0; j < 16; ++j) {
            int tj = t0 + 4 * j;
            if (tj > Tn - 4) tj = Tn - 4;      // pad slots have A=0
            rx[j] = *(const float4*)&xr[tj];
        }
        {
            int t1 = t0 + as, t2 = t1 + 32;
            float a1 = 0.f, a2 = 0.f;
            if (t1 < thi) { float df = lr - nb[t1]; a1 = __expf(fmaf(-5.f * df, df, -ml)) * il; }
            if (t2 < thi) { float df = lr - nb[t2]; a2 = __expf(fmaf(-5.f * df, df, -ml)) * il; }
            sA[as][al] = a1;
            sA[as + 32][al] = a2;
            if (dh == 0) {
                if (t1 < thi) ar[t1] = a1;
                if (t2 < thi) ar[t2] = a2;
            }
        }
        __syncthreads();                       // A ready
#pragma unroll
        for (int c = 0; c < 16; ++c) {
            float4 xv = rx[c];
#pragma unroll
            for (int e = 0; e < 4; ++e) {
                int s = 4 * c + e;
                float xs = ((const float*)&xv)[e];
                float4 a0 = *(const float4*)&sA[s][0];
                float4 a1 = *(const float4*)&sA[s][4];
                acc[0] = fmaf(xs, a0.x, acc[0]);
                acc[1] = fmaf(xs, a0.y, acc[1]);
                acc[2] = fmaf(xs, a0.z, acc[2]);
                acc[3] = fmaf(xs, a0.w, acc[3]);
                acc[4] = fmaf(xs, a1.x, acc[4]);
                acc[5] = fmaf(xs, a1.y, acc[5]);
                acc[6] = fmaf(xs, a1.z, acc[6]);
                acc[7] = fmaf(xs, a1.w, acc[7]);
            }
        }
        __syncthreads();                       // before next-iter overwrite
    }

    *(float4*)&z[zr]     = make_float4(acc[0], acc[1], acc[2], acc[3]);
    *(float4*)&z[zr + 4] = make_float4(acc[4], acc[5], acc[6], acc[7]);
}

extern "C" void kernel_launch(void* const* d_in, const int* in_sizes, int n_in,
                              void* d_out, int out_size, void* d_ws, size_t ws_size,
                              hipStream_t stream) {
    const float* x    = (const float*)d_in[0];
    const float* w    = (const float*)d_in[1];
    const int*   xlen = (const int*)d_in[3];
    float* out = (float*)d_out;

    const size_t OFF_Z     = 0;
    const size_t OFF_ZMASK = (size_t)Bn * Dn * Ln;
    const size_t OFF_ZLEN  = OFF_ZMASK + (size_t)Bn * Ln;
    const size_t OFF_ALIGN = OFF_ZLEN + Bn;
    const size_t OFF_LOSS  = OFF_ALIGN + (size_t)Bn * Ln * Tn;

    float* score     = (float*)d_ws;
    float* norm      = score + (size_t)Bn * Tn;
    float* loss_part = norm + (size_t)Bn * Tn;
    int*   wlo       = (int*)(loss_part + Bn);
    int*   whi       = wlo + Bn * NLT;
    float* sMw       = (float*)(whi + Bn * NLT);
    float* sIw       = sMw + (size_t)Bn * Ln;
    unsigned* flags  = (unsigned*)(sIw + (size_t)Bn * Ln);

    scorefill_kernel<<<512 + 4096 + Bn, 256, 0, stream>>>(
        x, w, xlen, score, (float4*)(out + OFF_ALIGN), flags,
        norm, loss_part, out + OFF_ZMASK, out + OFF_ZLEN,
        wlo, whi, sMw, sIw);
    z_kernel<<<Bn * NLT * 2, 256, 0, stream>>>(x, norm, xlen, wlo, whi,
                                               sMw, sIw, loss_part,
                                               out + OFF_ALIGN, out + OFF_Z,
                                               out + OFF_LOSS);
}

// Round 14
// 56.229 us; speedup vs baseline: 1.2265x; 1.2265x over previous
//
#include <hip/hip_runtime.h>
#include <cstddef>

#define Bn 16
#define Dn 512
#define Tn 2048
#define Ln 512
#define NLT 64      // l-tiles per b (Ln/8)

typedef float nfloat4 __attribute__((ext_vector_type(4)));  // for NT stores

// ---- K1 (merged): score (1024 blocks, 32-t chunks) + align NT-zero-fill --
__global__ __launch_bounds__(256) void scorefill_kernel(const float* __restrict__ x,
                                                        const float* __restrict__ w,
                                                        const int* __restrict__ xlen,
                                                        float* __restrict__ score,
                                                        float* __restrict__ align) {
    int bid = blockIdx.x;
    int tid = threadIdx.x;

    if (bid >= 1024) {                         // ---- fill role (4096 blocks)
        const size_t NT = (size_t)Bn * Ln * Tn / 4;      // floats per quarter
        nfloat4* a4 = (nfloat4*)align;
        size_t i = (size_t)(bid - 1024) * 256 + tid;
        nfloat4 z4 = {0.f, 0.f, 0.f, 0.f};
        __builtin_nontemporal_store(z4, &a4[i]);
        __builtin_nontemporal_store(z4, &a4[i + NT / 4]);
        __builtin_nontemporal_store(z4, &a4[i + 2 * (NT / 4)]);
        __builtin_nontemporal_store(z4, &a4[i + 3 * (NT / 4)]);
        return;
    }

    // ---- score role: block = (b, 32-t chunk); 32 dg x 16 d, 8 tq x 4 t
    int b   = bid >> 6;
    int tc  = bid & 63;
    int xl  = xlen[b];
    int t0c = tc * 32;
    if (t0c >= xl) {
        if (tid < 8)
            *(float4*)&score[b * Tn + t0c + tid * 4] = make_float4(0.f, 0.f, 0.f, 0.f);
        return;
    }
    int tq = tid & 7;
    int dg = tid >> 3;
    int t0 = t0c + tq * 4;
    const float* xb = x + (size_t)b * Dn * Tn + t0;
    float4 acc = make_float4(0.f, 0.f, 0.f, 0.f);
    int dbase = dg * 16;
#pragma unroll
    for (int i = 0; i < 16; ++i) {
        int d = dbase + i;
        float4 v = *(const float4*)&xb[(size_t)d * Tn];
        float wd = w[d];
        acc.x = fmaf(v.x, wd, acc.x);
        acc.y = fmaf(v.y, wd, acc.y);
        acc.z = fmaf(v.z, wd, acc.z);
        acc.w = fmaf(v.w, wd, acc.w);
    }
    __shared__ float4 red[32][8];
    __shared__ float4 red2[8][8];
    red[dg][tq] = acc;
    __syncthreads();
    if (tid < 64) {
        int q = tid & 7, g = tid >> 3;
        float4 s0 = red[g * 4 + 0][q], s1 = red[g * 4 + 1][q];
        float4 s2 = red[g * 4 + 2][q], s3 = red[g * 4 + 3][q];
        float4 s;
        s.x = (s0.x + s1.x) + (s2.x + s3.x);
        s.y = (s0.y + s1.y) + (s2.y + s3.y);
        s.z = (s0.z + s1.z) + (s2.z + s3.z);
        s.w = (s0.w + s1.w) + (s2.w + s3.w);
        red2[g][q] = s;
    }
    __syncthreads();
    if (tid < 8) {
        float4 s = red2[0][tid];
#pragma unroll
        for (int g = 1; g < 8; ++g) {
            float4 r = red2[g][tid];
            s.x += r.x; s.y += r.y; s.z += r.z; s.w += r.w;
        }
        int t = t0c + tid * 4;
        float4 o;
        o.x = (t + 0 < xl) ? __expf(s.x) : 0.f;
        o.y = (t + 1 < xl) ? __expf(s.y) : 0.f;
        o.z = (t + 2 < xl) ? __expf(s.z) : 0.f;
        o.w = (t + 3 < xl) ? __expf(s.w) : 0.f;
        *(float4*)&score[b * Tn + t] = o;
    }
}

// -------- K2: scan -> norm, loss, z_mask, z_len, windows, row softmax ----
__global__ __launch_bounds__(256) void scan_kernel(const float* __restrict__ score,
                                                   const int* __restrict__ xlen,
                                                   float* __restrict__ norm,
                                                   float* __restrict__ loss_part,
                                                   float* __restrict__ zmask_out,
                                                   float* __restrict__ zlen_out,
                                                   int* __restrict__ wlo,
                                                   int* __restrict__ whi,
                                                   float* __restrict__ sMout,
                                                   float* __restrict__ sIout) {
    int b = blockIdx.x, tid = threadIdx.x;
    int xl = xlen[b];
    int zl = (xl + 3) >> 2;
    const float* sc = score + b * Tn;

    __shared__ float sNorm[Tn];   // 8 KB
    __shared__ int   sTC[Ln];     // 2 KB

    float v[8]; float s = 0.f;
#pragma unroll
    for (int k = 0; k < 8; ++k) { v[k] = sc[tid * 8 + k]; s += v[k]; }

    float ps = s;
#pragma unroll
    for (int off = 1; off < 64; off <<= 1) {
        float n = __shfl_up(ps, off, 64);
        if ((tid & 63) >= off) ps += n;
    }
    __shared__ float wsum[4];
    if ((tid & 63) == 63) wsum[tid >> 6] = ps;
    __syncthreads();
    float base = 0.f;
#pragma unroll
    for (int wv = 0; wv < 4; ++wv) if (wv < (tid >> 6)) base += wsum[wv];
    float total = wsum[0] + wsum[1] + wsum[2] + wsum[3];
    float cum0  = sc[0];
    float scale = (float)(zl - 1) / (total - cum0);

    float run = base + ps - s;
    float nv[8];
#pragma unroll
    for (int k = 0; k < 8; ++k) {
        run += v[k];
        float xx = (run - cum0) * scale;
        nv[k] = xx;
        norm[b * Tn + tid * 8 + k] = xx;
        sNorm[tid * 8 + k] = xx;
    }

    float ls = 0.f;
#pragma unroll
    for (int k = 0; k < 8; ++k) {
        int t = tid * 8 + k;
        if (t >= 1 && t < xl) {
            float diff = v[k] * scale;
            ls += fmaxf(diff - 1.0f, 0.f);
        }
    }
#pragma unroll
    for (int off = 32; off; off >>= 1) ls += __shfl_down(ls, off, 64);
    __shared__ float lw[4];
    if ((tid & 63) == 0) lw[tid >> 6] = ls;

    for (int l = tid; l < Ln; l += 256)
        zmask_out[b * Ln + l] = (l * 4 < xl) ? 1.f : 0.f;
    if (tid == 0) zlen_out[b] = (float)zl;

    for (int i = tid; i < NLT; i += 256) {
        wlo[b * NLT + i] = xl;
        whi[b * NLT + i] = xl;
    }
    for (int l = tid; l < Ln; l += 256) sTC[l] = xl - 1;
    __syncthreads();
    if (tid == 0) loss_part[b] = (lw[0] + lw[1] + lw[2] + lw[3]) / (float)(xl - 1);

    // crossing detection (norm monotone non-decreasing => unique crossings)
#pragma unroll
    for (int k = 0; k < 8; ++k) {
        int t = tid * 8 + k;
        float vv = nv[k];
        float p  = (t == 0) ? -1e9f : sNorm[t - 1];
        int lsr = (int)floorf((p + 1.5f) * 0.125f) + 1; if (lsr < 0) lsr = 0;
        int ler = (int)floorf((vv + 1.5f) * 0.125f);    if (ler > NLT - 1) ler = NLT - 1;
        for (int lt = lsr; lt <= ler; ++lt) wlo[b * NLT + lt] = t;
        int hs = (int)ceilf((p - 8.5f) * 0.125f);       if (hs < 0) hs = 0;
        int he = (int)ceilf((vv - 8.5f) * 0.125f) - 1;  if (he > NLT - 1) he = NLT - 1;
        for (int lt = hs; lt <= he; ++lt) whi[b * NLT + lt] = t;
        int cs = (int)floorf(p) + 1;  if (cs < 0) cs = 0;
        int ce = (int)floorf(vv);     if (ce > Ln - 1) ce = Ln - 1;
        for (int l = cs; l <= ce; ++l) sTC[l] = t;
    }
    __syncthreads();

    // per-row exact max + truncated sum
    for (int l = tid; l < Ln; l += 256) {
        float mv = 0.f, iv = 0.f;
        if (l < zl) {
            int tc2 = sTC[l];
            float d1 = (float)l - sNorm[tc2];
            float m  = -5.f * d1 * d1;
            if (tc2 > 0) { float d0v = (float)l - sNorm[tc2 - 1]; float c = -5.f * d0v * d0v; m = fmaxf(m, c); }
            int lo = (l >= 2) ? sTC[l - 2] : 0;
            int hi = (l + 2 <= zl - 1) ? sTC[l + 2] : xl;
            int tcm1 = (tc2 > 0) ? tc2 - 1 : 0;
            if (lo > tcm1) lo = tcm1;
            int tcp1 = (tc2 + 1 < xl) ? tc2 + 1 : xl;
            if (hi < tcp1) hi = tcp1;
            float ssum = 0.f;
            for (int t = lo; t < hi; ++t) {
                float df = (float)l - sNorm[t];
                ssum += __expf(-5.f * df * df - m);
            }
            mv = m; iv = 1.f / ssum;
        }
        sMout[b * Ln + l] = mv;
        sIout[b * Ln + l] = iv;
    }
}

// -------- K3: z GEMM + alignment window writes + loss finalize -----------
__global__ __launch_bounds__(256) void z_kernel(const float* __restrict__ x,
                                                const float* __restrict__ norm,
                                                const int* __restrict__ xlen,
                                                const int* __restrict__ wlo,
                                                const int* __restrict__ whi,
                                                const float* __restrict__ sM,
                                                const float* __restrict__ sI,
                                                const float* __restrict__ loss_part,
                                                float* __restrict__ align,
                                                float* __restrict__ z,
                                                float* __restrict__ out_loss) {
    int tid = threadIdx.x;
    int bid = blockIdx.x;
    if (bid == 0 && tid == 0) {
        float s = 0.f;
        for (int i = 0; i < Bn; ++i) s += loss_part[i];
        out_loss[0] = s / (float)Bn;
    }
    int swz = (bid & 7) * 256 + (bid >> 3);   // bijective: 2048 = 8*256
    int b   = swz >> 7;
    int rem = swz & 127;
    int lt  = rem >> 1;
    int dh  = rem & 1;
    int l0  = lt * 8;
    int xl  = xlen[b];
    int zl  = (xl + 3) >> 2;
    int d   = dh * 256 + tid;
    size_t zr = (size_t)(b * Dn + d) * Ln + l0;

    if (l0 >= zl) {
        float4 z4 = make_float4(0.f, 0.f, 0.f, 0.f);
        *(float4*)&z[zr] = z4; *(float4*)&z[zr + 4] = z4;
        return;
    }

    int tlo = wlo[b * NLT + lt];
    int thi = whi[b * NLT + lt];
    if (thi > xl) thi = xl;
    int tA = tlo & ~15;                        // 64B-aligned window start

    __shared__ float sA[64][8];                // 2 KB, A[s][l]
    const float* nb = norm + b * Tn;
    const float* xr = x + (size_t)(b * Dn + d) * Tn;

    int al = tid >> 5;                         // A-build: l row 0..7
    int as = tid & 31;                         // A-build: slots as, as+32
    float ml = sM[b * Ln + l0 + al];
    float il = sI[b * Ln + l0 + al];
    float lr = (float)(l0 + al);
    float* ar = align + (size_t)(b * Ln + l0 + al) * Tn;

    float acc[8] = {};
    float4 rx[16];

    for (int t0 = tA; t0 < thi; t0 += 64) {    // normally ONE iteration
#pragma unroll
        for (int j = 0; j < 16; ++j) {
            int tj = t0 + 4 * j;
            if (tj > Tn - 4) tj = Tn - 4;      // pad slots have A=0
            rx[j] = *(const float4*)&xr[tj];
        }
        {
            int t1 = t0 + as, t2 = t1 + 32;
            float a1 = 0.f, a2 = 0.f;
            if (t1 < thi) { float df = lr - nb[t1]; a1 = __expf(fmaf(-5.f * df, df, -ml)) * il; }
            if (t2 < thi) { float df = lr - nb[t2]; a2 = __expf(fmaf(-5.f * df, df, -ml)) * il; }
            sA[as][al] = a1;
            sA[as + 32][al] = a2;
            if (dh == 0) {
                if (t1 < thi) ar[t1] = a1;
                if (t2 < thi) ar[t2] = a2;
            }
        }
        __syncthreads();                       // A ready
#pragma unroll
        for (int c = 0; c < 16; ++c) {
            float4 xv = rx[c];
#pragma unroll
            for (int e = 0; e < 4; ++e) {
                int s = 4 * c + e;
                float xs = ((const float*)&xv)[e];
                float4 a0 = *(const float4*)&sA[s][0];
                float4 a1 = *(const float4*)&sA[s][4];
                acc[0] = fmaf(xs, a0.x, acc[0]);
                acc[1] = fmaf(xs, a0.y, acc[1]);
                acc[2] = fmaf(xs, a0.z, acc[2]);
                acc[3] = fmaf(xs, a0.w, acc[3]);
                acc[4] = fmaf(xs, a1.x, acc[4]);
                acc[5] = fmaf(xs, a1.y, acc[5]);
                acc[6] = fmaf(xs, a1.z, acc[6]);
                acc[7] = fmaf(xs, a1.w, acc[7]);
            }
        }
        __syncthreads();                       // before next-iter overwrite
    }

    *(float4*)&z[zr]     = make_float4(acc[0], acc[1], acc[2], acc[3]);
    *(float4*)&z[zr + 4] = make_float4(acc[4], acc[5], acc[6], acc[7]);
}

extern "C" void kernel_launch(void* const* d_in, const int* in_sizes, int n_in,
                              void* d_out, int out_size, void* d_ws, size_t ws_size,
                              hipStream_t stream) {
    const float* x    = (const float*)d_in[0];
    const float* w    = (const float*)d_in[1];
    const int*   xlen = (const int*)d_in[3];
    float* out = (float*)d_out;

    const size_t OFF_Z     = 0;
    const size_t OFF_ZMASK = (size_t)Bn * Dn * Ln;
    const size_t OFF_ZLEN  = OFF_ZMASK + (size_t)Bn * Ln;
    const size_t OFF_ALIGN = OFF_ZLEN + Bn;
    const size_t OFF_LOSS  = OFF_ALIGN + (size_t)Bn * Ln * Tn;

    float* score     = (float*)d_ws;
    float* norm      = score + (size_t)Bn * Tn;
    float* loss_part = norm + (size_t)Bn * Tn;
    int*   wlo       = (int*)(loss_part + Bn);
    int*   whi       = wlo + Bn * NLT;
    float* sMw       = (float*)(whi + Bn * NLT);
    float* sIw       = sMw + (size_t)Bn * Ln;

    scorefill_kernel<<<1024 + 4096, 256, 0, stream>>>(x, w, xlen, score,
                                                      out + OFF_ALIGN);
    scan_kernel<<<Bn, 256, 0, stream>>>(score, xlen, norm, loss_part,
                                        out + OFF_ZMASK, out + OFF_ZLEN,
                                        wlo, whi, sMw, sIw);
    z_kernel<<<Bn * NLT * 2, 256, 0, stream>>>(x, norm, xlen, wlo, whi,
                                               sMw, sIw, loss_part,
                                               out + OFF_ALIGN, out + OFF_Z,
                                               out + OFF_LOSS);
}

// Round 15
// 53.197 us; speedup vs baseline: 1.2964x; 1.0570x over previous
//
#include <hip/hip_runtime.h>
#include <cstddef>

#define Bn 16
#define Dn 512
#define Tn 2048
#define Ln 512
#define NLT 64      // l-tiles per b (Ln/8)

// ---- K1 (merged): score (512 blocks) + DEAD align rows (l >= zl) --------
// Dead rows depend only on xlen -> fillable before scan. Live rows' zeros
// are written by z_kernel (window-aware, overlapped with the GEMM).
__global__ __launch_bounds__(256) void scorefill_kernel(const float* __restrict__ x,
                                                        const float* __restrict__ w,
                                                        const int* __restrict__ xlen,
                                                        float* __restrict__ score,
                                                        float* __restrict__ align) {
    int bid = blockIdx.x;
    int tid = threadIdx.x;

    if (bid >= 512) {                          // ---- dead-row fill role ----
        int r0 = (bid - 512) * 2;              // two align rows per block
        float4 z4 = make_float4(0.f, 0.f, 0.f, 0.f);
#pragma unroll
        for (int rr = 0; rr < 2; ++rr) {
            int r = r0 + rr;
            int b = r >> 9, l = r & 511;
            int zl = (xlen[b] + 3) >> 2;
            if (l < zl) continue;              // live row: z_kernel writes it
            float4* row4 = (float4*)(align + (size_t)r * Tn);
            row4[tid]       = z4;
            row4[tid + 256] = z4;
        }
        return;
    }

    // ---- score role: block = (b, 64-t chunk) ----
    int b   = bid >> 5;
    int tc  = bid & 31;
    int xl  = xlen[b];
    int t0c = tc * 64;
    if (t0c >= xl) {
        if (tid < 16)
            *(float4*)&score[b * Tn + t0c + tid * 4] = make_float4(0.f, 0.f, 0.f, 0.f);
        return;
    }
    int tq  = tid & 15;
    int dg  = tid >> 4;
    int t0  = t0c + tq * 4;
    const float* xb = x + (size_t)b * Dn * Tn + t0;
    float4 acc = make_float4(0.f, 0.f, 0.f, 0.f);
    int dbase = dg * 32;
#pragma unroll 8
    for (int i = 0; i < 32; ++i) {
        int d = dbase + i;
        float4 v = *(const float4*)&xb[(size_t)d * Tn];
        float wd = w[d];
        acc.x = fmaf(v.x, wd, acc.x);
        acc.y = fmaf(v.y, wd, acc.y);
        acc.z = fmaf(v.z, wd, acc.z);
        acc.w = fmaf(v.w, wd, acc.w);
    }
    __shared__ float4 red[16][16];
    red[dg][tq] = acc;
    __syncthreads();
    if (tid < 16) {
        float4 s = red[0][tid];
#pragma unroll
        for (int g = 1; g < 16; ++g) {
            float4 r = red[g][tid];
            s.x += r.x; s.y += r.y; s.z += r.z; s.w += r.w;
        }
        int t = t0c + tid * 4;
        float4 o;
        o.x = (t + 0 < xl) ? __expf(s.x) : 0.f;
        o.y = (t + 1 < xl) ? __expf(s.y) : 0.f;
        o.z = (t + 2 < xl) ? __expf(s.z) : 0.f;
        o.w = (t + 3 < xl) ? __expf(s.w) : 0.f;
        *(float4*)&score[b * Tn + t] = o;
    }
}

// -------- K2: scan -> norm, loss, z_mask, z_len, windows, row softmax ----
__global__ __launch_bounds__(256) void scan_kernel(const float* __restrict__ score,
                                                   const int* __restrict__ xlen,
                                                   float* __restrict__ norm,
                                                   float* __restrict__ loss_part,
                                                   float* __restrict__ zmask_out,
                                                   float* __restrict__ zlen_out,
                                                   int* __restrict__ wlo,
                                                   int* __restrict__ whi,
                                                   float* __restrict__ sMout,
                                                   float* __restrict__ sIout) {
    int b = blockIdx.x, tid = threadIdx.x;
    int xl = xlen[b];
    int zl = (xl + 3) >> 2;
    const float* sc = score + b * Tn;

    __shared__ float sNorm[Tn];   // 8 KB
    __shared__ int   sTC[Ln];     // 2 KB

    float v[8]; float s = 0.f;
#pragma unroll
    for (int k = 0; k < 8; ++k) { v[k] = sc[tid * 8 + k]; s += v[k]; }

    float ps = s;
#pragma unroll
    for (int off = 1; off < 64; off <<= 1) {
        float n = __shfl_up(ps, off, 64);
        if ((tid & 63) >= off) ps += n;
    }
    __shared__ float wsum[4];
    if ((tid & 63) == 63) wsum[tid >> 6] = ps;
    __syncthreads();
    float base = 0.f;
#pragma unroll
    for (int wv = 0; wv < 4; ++wv) if (wv < (tid >> 6)) base += wsum[wv];
    float total = wsum[0] + wsum[1] + wsum[2] + wsum[3];
    float cum0  = sc[0];
    float scale = (float)(zl - 1) / (total - cum0);

    float run = base + ps - s;
    float nv[8];
#pragma unroll
    for (int k = 0; k < 8; ++k) {
        run += v[k];
        float xx = (run - cum0) * scale;
        nv[k] = xx;
        norm[b * Tn + tid * 8 + k] = xx;
        sNorm[tid * 8 + k] = xx;
    }

    float ls = 0.f;
#pragma unroll
    for (int k = 0; k < 8; ++k) {
        int t = tid * 8 + k;
        if (t >= 1 && t < xl) {
            float diff = v[k] * scale;
            ls += fmaxf(diff - 1.0f, 0.f);
        }
    }
#pragma unroll
    for (int off = 32; off; off >>= 1) ls += __shfl_down(ls, off, 64);
    __shared__ float lw[4];
    if ((tid & 63) == 0) lw[tid >> 6] = ls;

    for (int l = tid; l < Ln; l += 256)
        zmask_out[b * Ln + l] = (l * 4 < xl) ? 1.f : 0.f;
    if (tid == 0) zlen_out[b] = (float)zl;

    for (int i = tid; i < NLT; i += 256) {
        wlo[b * NLT + i] = xl;
        whi[b * NLT + i] = xl;
    }
    for (int l = tid; l < Ln; l += 256) sTC[l] = xl - 1;
    __syncthreads();
    if (tid == 0) loss_part[b] = (lw[0] + lw[1] + lw[2] + lw[3]) / (float)(xl - 1);

    // crossing detection (norm monotone non-decreasing => unique crossings)
#pragma unroll
    for (int k = 0; k < 8; ++k) {
        int t = tid * 8 + k;
        float vv = nv[k];
        float p  = (t == 0) ? -1e9f : sNorm[t - 1];
        int lsr = (int)floorf((p + 1.5f) * 0.125f) + 1; if (lsr < 0) lsr = 0;
        int ler = (int)floorf((vv + 1.5f) * 0.125f);    if (ler > NLT - 1) ler = NLT - 1;
        for (int lt = lsr; lt <= ler; ++lt) wlo[b * NLT + lt] = t;
        int hs = (int)ceilf((p - 8.5f) * 0.125f);       if (hs < 0) hs = 0;
        int he = (int)ceilf((vv - 8.5f) * 0.125f) - 1;  if (he > NLT - 1) he = NLT - 1;
        for (int lt = hs; lt <= he; ++lt) whi[b * NLT + lt] = t;
        int cs = (int)floorf(p) + 1;  if (cs < 0) cs = 0;
        int ce = (int)floorf(vv);     if (ce > Ln - 1) ce = Ln - 1;
        for (int l = cs; l <= ce; ++l) sTC[l] = t;
    }
    __syncthreads();

    // per-row exact max + truncated sum
    for (int l = tid; l < Ln; l += 256) {
        float mv = 0.f, iv = 0.f;
        if (l < zl) {
            int tc2 = sTC[l];
            float d1 = (float)l - sNorm[tc2];
            float m  = -5.f * d1 * d1;
            if (tc2 > 0) { float d0v = (float)l - sNorm[tc2 - 1]; float c = -5.f * d0v * d0v; m = fmaxf(m, c); }
            int lo = (l >= 2) ? sTC[l - 2] : 0;
            int hi = (l + 2 <= zl - 1) ? sTC[l + 2] : xl;
            int tcm1 = (tc2 > 0) ? tc2 - 1 : 0;
            if (lo > tcm1) lo = tcm1;
            int tcp1 = (tc2 + 1 < xl) ? tc2 + 1 : xl;
            if (hi < tcp1) hi = tcp1;
            float ssum = 0.f;
            for (int t = lo; t < hi; ++t) {
                float df = (float)l - sNorm[t];
                ssum += __expf(-5.f * df * df - m);
            }
            mv = m; iv = 1.f / ssum;
        }
        sMout[b * Ln + l] = mv;
        sIout[b * Ln + l] = iv;
    }
}

// -------- K3: z GEMM + LIVE align rows (values + outside-window zeros) ---
// Per live tile: dh0 writes zeros [0,tA) + [start4,mid4) + scalar head
// [thi,start4) + window values [tA,thi); dh1 writes zeros [mid4,Tn).
// Disjoint ranges; dead rows were zeroed by K1 (duplicate zeros harmless,
// kernels are sequential on the stream).
__global__ __launch_bounds__(256) void z_kernel(const float* __restrict__ x,
                                                const float* __restrict__ norm,
                                                const int* __restrict__ xlen,
                                                const int* __restrict__ wlo,
                                                const int* __restrict__ whi,
                                                const float* __restrict__ sM,
                                                const float* __restrict__ sI,
                                                const float* __restrict__ loss_part,
                                                float* __restrict__ align,
                                                float* __restrict__ z,
                                                float* __restrict__ out_loss) {
    int tid = threadIdx.x;
    int bid = blockIdx.x;
    if (bid == 0 && tid == 0) {
        float s = 0.f;
        for (int i = 0; i < Bn; ++i) s += loss_part[i];
        out_loss[0] = s / (float)Bn;
    }
    int swz = (bid & 7) * 256 + (bid >> 3);   // bijective: 2048 = 8*256
    int b   = swz >> 7;
    int rem = swz & 127;
    int lt  = rem >> 1;
    int dh  = rem & 1;
    int l0  = lt * 8;
    int xl  = xlen[b];
    int zl  = (xl + 3) >> 2;
    int d   = dh * 256 + tid;
    size_t zr = (size_t)(b * Dn + d) * Ln + l0;

    if (l0 >= zl) {                            // dead tile: K1 zeroed align
        float4 z4 = make_float4(0.f, 0.f, 0.f, 0.f);
        *(float4*)&z[zr] = z4; *(float4*)&z[zr + 4] = z4;
        return;
    }

    int tlo = wlo[b * NLT + lt];
    int thi = whi[b * NLT + lt];
    if (thi > xl) thi = xl;
    int tA = tlo & ~15;                        // 64B-aligned window start

    // ---- outside-window zero-fill for this tile's 8 align rows ----
    {
        int start4 = (thi + 3) & ~3;           // first aligned q after thi
        if (start4 > Tn) start4 = Tn;
        int rest   = Tn - start4 - tA;         // balance dh0 (has tA) vs dh1
        if (rest < 0) rest = 0;
        int mid4   = start4 + ((rest >> 3) << 2);
        int row    = tid >> 5, lane32 = tid & 31;
        float* arw = align + (size_t)(b * Ln + l0 + row) * Tn;
        float4 z4f = make_float4(0.f, 0.f, 0.f, 0.f);
        if (dh == 0) {
            for (int q = lane32; q < (tA >> 2); q += 32)
                ((float4*)arw)[q] = z4f;
            if (thi + lane32 < start4) arw[thi + lane32] = 0.f;   // <=3 head
            for (int q = (start4 >> 2) + lane32; q < (mid4 >> 2); q += 32)
                ((float4*)arw)[q] = z4f;
        } else {
            for (int q = (mid4 >> 2) + lane32; q < (Tn >> 2); q += 32)
                ((float4*)arw)[q] = z4f;
        }
    }

    __shared__ float sA[64][8];                // 2 KB, A[s][l]
    const float* nb = norm + b * Tn;
    const float* xr = x + (size_t)(b * Dn + d) * Tn;

    int al = tid >> 5;                         // A-build: l row 0..7
    int as = tid & 31;                         // A-build: slots as, as+32
    float ml = sM[b * Ln + l0 + al];
    float il = sI[b * Ln + l0 + al];
    float lr = (float)(l0 + al);
    float* ar = align + (size_t)(b * Ln + l0 + al) * Tn;

    float acc[8] = {};
    float4 rx[16];

    for (int t0 = tA; t0 < thi; t0 += 64) {    // normally ONE iteration
#pragma unroll
        for (int j = 0; j < 16; ++j) {
            int tj = t0 + 4 * j;
            if (tj > Tn - 4) tj = Tn - 4;      // pad slots have A=0
            rx[j] = *(const float4*)&xr[tj];
        }
        {
            int t1 = t0 + as, t2 = t1 + 32;
            float a1 = 0.f, a2 = 0.f;
            if (t1 < thi) { float df = lr - nb[t1]; a1 = __expf(fmaf(-5.f * df, df, -ml)) * il; }
            if (t2 < thi) { float df = lr - nb[t2]; a2 = __expf(fmaf(-5.f * df, df, -ml)) * il; }
            sA[as][al] = a1;
            sA[as + 32][al] = a2;
            if (dh == 0) {
                if (t1 < thi) ar[t1] = a1;
                if (t2 < thi) ar[t2] = a2;
            }
        }
        __syncthreads();                       // A ready
#pragma unroll
        for (int c = 0; c < 16; ++c) {
            float4 xv = rx[c];
#pragma unroll
            for (int e = 0; e < 4; ++e) {
                int s = 4 * c + e;
                float xs = ((const float*)&xv)[e];
                float4 a0 = *(const float4*)&sA[s][0];
                float4 a1 = *(const float4*)&sA[s][4];
                acc[0] = fmaf(xs, a0.x, acc[0]);
                acc[1] = fmaf(xs, a0.y, acc[1]);
                acc[2] = fmaf(xs, a0.z, acc[2]);
                acc[3] = fmaf(xs, a0.w, acc[3]);
                acc[4] = fmaf(xs, a1.x, acc[4]);
                acc[5] = fmaf(xs, a1.y, acc[5]);
                acc[6] = fmaf(xs, a1.z, acc[6]);
                acc[7] = fmaf(xs, a1.w, acc[7]);
            }
        }
        __syncthreads();                       // before next-iter overwrite
    }

    *(float4*)&z[zr]     = make_float4(acc[0], acc[1], acc[2], acc[3]);
    *(float4*)&z[zr + 4] = make_float4(acc[4], acc[5], acc[6], acc[7]);
}

extern "C" void kernel_launch(void* const* d_in, const int* in_sizes, int n_in,
                              void* d_out, int out_size, void* d_ws, size_t ws_size,
                              hipStream_t stream) {
    const float* x    = (const float*)d_in[0];
    const float* w    = (const float*)d_in[1];
    const int*   xlen = (const int*)d_in[3];
    float* out = (float*)d_out;

    const size_t OFF_Z     = 0;
    const size_t OFF_ZMASK = (size_t)Bn * Dn * Ln;
    const size_t OFF_ZLEN  = OFF_ZMASK + (size_t)Bn * Ln;
    const size_t OFF_ALIGN = OFF_ZLEN + Bn;
    const size_t OFF_LOSS  = OFF_ALIGN + (size_t)Bn * Ln * Tn;

    float* score     = (float*)d_ws;
    float* norm      = score + (size_t)Bn * Tn;
    float* loss_part = norm + (size_t)Bn * Tn;
    int*   wlo       = (int*)(loss_part + Bn);
    int*   whi       = wlo + Bn * NLT;
    float* sMw       = (float*)(whi + Bn * NLT);
    float* sIw       = sMw + (size_t)Bn * Ln;

    scorefill_kernel<<<512 + 4096, 256, 0, stream>>>(x, w, xlen, score,
                                                     out + OFF_ALIGN);
    scan_kernel<<<Bn, 256, 0, stream>>>(score, xlen, norm, loss_part,
                                        out + OFF_ZMASK, out + OFF_ZLEN,
                                        wlo, whi, sMw, sIw);
    z_kernel<<<Bn * NLT * 2, 256, 0, stream>>>(x, norm, xlen, wlo, whi,
                                               sMw, sIw, loss_part,
                                               out + OFF_ALIGN, out + OFF_Z,
                                               out + OFF_LOSS);
}

// Round 16
// 52.811 us; speedup vs baseline: 1.3059x; 1.0073x over previous
//
#include <hip/hip_runtime.h>
#include <cstddef>

#define Bn 16
#define Dn 512
#define Tn 2048
#define Ln 512
#define NLT 64      // l-tiles per b (Ln/8)

// ---- K1 (merged): score (1024 blocks, batch-loaded) + DEAD align rows ---
__global__ __launch_bounds__(256) void scorefill_kernel(const float* __restrict__ x,
                                                        const float* __restrict__ w,
                                                        const int* __restrict__ xlen,
                                                        float* __restrict__ score,
                                                        float* __restrict__ align) {
    int bid = blockIdx.x;
    int tid = threadIdx.x;

    if (bid >= 1024) {                         // ---- dead-row fill role ----
        int r0 = (bid - 1024) * 2;             // two align rows per block
        float4 z4 = make_float4(0.f, 0.f, 0.f, 0.f);
#pragma unroll
        for (int rr = 0; rr < 2; ++rr) {
            int r = r0 + rr;
            int b = r >> 9, l = r & 511;
            int zl = (xlen[b] + 3) >> 2;
            if (l < zl) continue;              // live row: z_kernel writes it
            float4* row4 = (float4*)(align + (size_t)r * Tn);
            row4[tid]       = z4;
            row4[tid + 256] = z4;
        }
        return;
    }

    // ---- score role: block = (b, 32-t chunk); 32 dg x 16 d, 8 tq x 4 t --
    // All 16 x-loads batched into rx[16] -> 16 independent loads in flight.
    int b   = bid >> 6;
    int tc  = bid & 63;
    int xl  = xlen[b];
    int t0c = tc * 32;
    if (t0c >= xl) {
        if (tid < 8)
            *(float4*)&score[b * Tn + t0c + tid * 4] = make_float4(0.f, 0.f, 0.f, 0.f);
        return;
    }
    int tq = tid & 7;
    int dg = tid >> 3;
    int t0 = t0c + tq * 4;
    const float* xb = x + (size_t)b * Dn * Tn + (size_t)(dg * 16) * Tn + t0;
    const float* wb = w + dg * 16;

    float4 rx[16];
#pragma unroll
    for (int i = 0; i < 16; ++i)
        rx[i] = *(const float4*)&xb[(size_t)i * Tn];

    float4 acc = make_float4(0.f, 0.f, 0.f, 0.f);
#pragma unroll
    for (int i = 0; i < 16; ++i) {
        float wd = wb[i];
        acc.x = fmaf(rx[i].x, wd, acc.x);
        acc.y = fmaf(rx[i].y, wd, acc.y);
        acc.z = fmaf(rx[i].z, wd, acc.z);
        acc.w = fmaf(rx[i].w, wd, acc.w);
    }

    __shared__ float4 red[32][8];
    __shared__ float4 red2[8][8];
    red[dg][tq] = acc;
    __syncthreads();
    if (tid < 64) {
        int q = tid & 7, g = tid >> 3;
        float4 s0 = red[g * 4 + 0][q], s1 = red[g * 4 + 1][q];
        float4 s2 = red[g * 4 + 2][q], s3 = red[g * 4 + 3][q];
        float4 s;
        s.x = (s0.x + s1.x) + (s2.x + s3.x);
        s.y = (s0.y + s1.y) + (s2.y + s3.y);
        s.z = (s0.z + s1.z) + (s2.z + s3.z);
        s.w = (s0.w + s1.w) + (s2.w + s3.w);
        red2[g][q] = s;
    }
    __syncthreads();
    if (tid < 8) {
        float4 s = red2[0][tid];
#pragma unroll
        for (int g = 1; g < 8; ++g) {
            float4 r = red2[g][tid];
            s.x += r.x; s.y += r.y; s.z += r.z; s.w += r.w;
        }
        int t = t0c + tid * 4;
        float4 o;
        o.x = (t + 0 < xl) ? __expf(s.x) : 0.f;
        o.y = (t + 1 < xl) ? __expf(s.y) : 0.f;
        o.z = (t + 2 < xl) ? __expf(s.z) : 0.f;
        o.w = (t + 3 < xl) ? __expf(s.w) : 0.f;
        *(float4*)&score[b * Tn + t] = o;
    }
}

// -------- K2: scan -> norm, loss, z_mask, z_len, windows, row softmax ----
__global__ __launch_bounds__(256) void scan_kernel(const float* __restrict__ score,
                                                   const int* __restrict__ xlen,
                                                   float* __restrict__ norm,
                                                   float* __restrict__ loss_part,
                                                   float* __restrict__ zmask_out,
                                                   float* __restrict__ zlen_out,
                                                   int* __restrict__ wlo,
                                                   int* __restrict__ whi,
                                                   float* __restrict__ sMout,
                                                   float* __restrict__ sIout) {
    int b = blockIdx.x, tid = threadIdx.x;
    int xl = xlen[b];
    int zl = (xl + 3) >> 2;
    const float* sc = score + b * Tn;

    __shared__ float sNorm[Tn];   // 8 KB
    __shared__ int   sTC[Ln];     // 2 KB

    float v[8]; float s = 0.f;
#pragma unroll
    for (int k = 0; k < 8; ++k) { v[k] = sc[tid * 8 + k]; s += v[k]; }

    float ps = s;
#pragma unroll
    for (int off = 1; off < 64; off <<= 1) {
        float n = __shfl_up(ps, off, 64);
        if ((tid & 63) >= off) ps += n;
    }
    __shared__ float wsum[4];
    if ((tid & 63) == 63) wsum[tid >> 6] = ps;
    __syncthreads();
    float base = 0.f;
#pragma unroll
    for (int wv = 0; wv < 4; ++wv) if (wv < (tid >> 6)) base += wsum[wv];
    float total = wsum[0] + wsum[1] + wsum[2] + wsum[3];
    float cum0  = sc[0];
    float scale = (float)(zl - 1) / (total - cum0);

    float run = base + ps - s;
    float nv[8];
#pragma unroll
    for (int k = 0; k < 8; ++k) {
        run += v[k];
        float xx = (run - cum0) * scale;
        nv[k] = xx;
        norm[b * Tn + tid * 8 + k] = xx;
        sNorm[tid * 8 + k] = xx;
    }

    float ls = 0.f;
#pragma unroll
    for (int k = 0; k < 8; ++k) {
        int t = tid * 8 + k;
        if (t >= 1 && t < xl) {
            float diff = v[k] * scale;
            ls += fmaxf(diff - 1.0f, 0.f);
        }
    }
#pragma unroll
    for (int off = 32; off; off >>= 1) ls += __shfl_down(ls, off, 64);
    __shared__ float lw[4];
    if ((tid & 63) == 0) lw[tid >> 6] = ls;

    for (int l = tid; l < Ln; l += 256)
        zmask_out[b * Ln + l] = (l * 4 < xl) ? 1.f : 0.f;
    if (tid == 0) zlen_out[b] = (float)zl;

    for (int i = tid; i < NLT; i += 256) {
        wlo[b * NLT + i] = xl;
        whi[b * NLT + i] = xl;
    }
    for (int l = tid; l < Ln; l += 256) sTC[l] = xl - 1;
    __syncthreads();
    if (tid == 0) loss_part[b] = (lw[0] + lw[1] + lw[2] + lw[3]) / (float)(xl - 1);

    // crossing detection (norm monotone non-decreasing => unique crossings)
#pragma unroll
    for (int k = 0; k < 8; ++k) {
        int t = tid * 8 + k;
        float vv = nv[k];
        float p  = (t == 0) ? -1e9f : sNorm[t - 1];
        int lsr = (int)floorf((p + 1.5f) * 0.125f) + 1; if (lsr < 0) lsr = 0;
        int ler = (int)floorf((vv + 1.5f) * 0.125f);    if (ler > NLT - 1) ler = NLT - 1;
        for (int lt = lsr; lt <= ler; ++lt) wlo[b * NLT + lt] = t;
        int hs = (int)ceilf((p - 8.5f) * 0.125f);       if (hs < 0) hs = 0;
        int he = (int)ceilf((vv - 8.5f) * 0.125f) - 1;  if (he > NLT - 1) he = NLT - 1;
        for (int lt = hs; lt <= he; ++lt) whi[b * NLT + lt] = t;
        int cs = (int)floorf(p) + 1;  if (cs < 0) cs = 0;
        int ce = (int)floorf(vv);     if (ce > Ln - 1) ce = Ln - 1;
        for (int l = cs; l <= ce; ++l) sTC[l] = t;
    }
    __syncthreads();

    // per-row exact max + truncated sum
    for (int l = tid; l < Ln; l += 256) {
        float mv = 0.f, iv = 0.f;
        if (l < zl) {
            int tc2 = sTC[l];
            float d1 = (float)l - sNorm[tc2];
            float m  = -5.f * d1 * d1;
            if (tc2 > 0) { float d0v = (float)l - sNorm[tc2 - 1]; float c = -5.f * d0v * d0v; m = fmaxf(m, c); }
            int lo = (l >= 2) ? sTC[l - 2] : 0;
            int hi = (l + 2 <= zl - 1) ? sTC[l + 2] : xl;
            int tcm1 = (tc2 > 0) ? tc2 - 1 : 0;
            if (lo > tcm1) lo = tcm1;
            int tcp1 = (tc2 + 1 < xl) ? tc2 + 1 : xl;
            if (hi < tcp1) hi = tcp1;
            float ssum = 0.f;
            for (int t = lo; t < hi; ++t) {
                float df = (float)l - sNorm[t];
                ssum += __expf(-5.f * df * df - m);
            }
            mv = m; iv = 1.f / ssum;
        }
        sMout[b * Ln + l] = mv;
        sIout[b * Ln + l] = iv;
    }
}

// -------- K3: z GEMM + LIVE align rows (values + outside-window zeros) ---
__global__ __launch_bounds__(256) void z_kernel(const float* __restrict__ x,
                                                const float* __restrict__ norm,
                                                const int* __restrict__ xlen,
                                                const int* __restrict__ wlo,
                                                const int* __restrict__ whi,
                                                const float* __restrict__ sM,
                                                const float* __restrict__ sI,
                                                const float* __restrict__ loss_part,
                                                float* __restrict__ align,
                                                float* __restrict__ z,
                                                float* __restrict__ out_loss) {
    int tid = threadIdx.x;
    int bid = blockIdx.x;
    if (bid == 0 && tid == 0) {
        float s = 0.f;
        for (int i = 0; i < Bn; ++i) s += loss_part[i];
        out_loss[0] = s / (float)Bn;
    }
    int swz = (bid & 7) * 256 + (bid >> 3);   // bijective: 2048 = 8*256
    int b   = swz >> 7;
    int rem = swz & 127;
    int lt  = rem >> 1;
    int dh  = rem & 1;
    int l0  = lt * 8;
    int xl  = xlen[b];
    int zl  = (xl + 3) >> 2;
    int d   = dh * 256 + tid;
    size_t zr = (size_t)(b * Dn + d) * Ln + l0;

    if (l0 >= zl) {                            // dead tile: K1 zeroed align
        float4 z4 = make_float4(0.f, 0.f, 0.f, 0.f);
        *(float4*)&z[zr] = z4; *(float4*)&z[zr + 4] = z4;
        return;
    }

    int tlo = wlo[b * NLT + lt];
    int thi = whi[b * NLT + lt];
    if (thi > xl) thi = xl;
    int tA = tlo & ~15;                        // 64B-aligned window start

    // ---- outside-window zero-fill for this tile's 8 align rows ----
    {
        int start4 = (thi + 3) & ~3;
        if (start4 > Tn) start4 = Tn;
        int rest   = Tn - start4 - tA;
        if (rest < 0) rest = 0;
        int mid4   = start4 + ((rest >> 3) << 2);
        int row    = tid >> 5, lane32 = tid & 31;
        float* arw = align + (size_t)(b * Ln + l0 + row) * Tn;
        float4 z4f = make_float4(0.f, 0.f, 0.f, 0.f);
        if (dh == 0) {
            for (int q = lane32; q < (tA >> 2); q += 32)
                ((float4*)arw)[q] = z4f;
            if (thi + lane32 < start4) arw[thi + lane32] = 0.f;
            for (int q = (start4 >> 2) + lane32; q < (mid4 >> 2); q += 32)
                ((float4*)arw)[q] = z4f;
        } else {
            for (int q = (mid4 >> 2) + lane32; q < (Tn >> 2); q += 32)
                ((float4*)arw)[q] = z4f;
        }
    }

    __shared__ float sA[64][8];                // 2 KB, A[s][l]
    const float* nb = norm + b * Tn;
    const float* xr = x + (size_t)(b * Dn + d) * Tn;

    int al = tid >> 5;
    int as = tid & 31;
    float ml = sM[b * Ln + l0 + al];
    float il = sI[b * Ln + l0 + al];
    float lr = (float)(l0 + al);
    float* ar = align + (size_t)(b * Ln + l0 + al) * Tn;

    float acc[8] = {};
    float4 rx[16];

    for (int t0 = tA; t0 < thi; t0 += 64) {    // normally ONE iteration
#pragma unroll
        for (int j = 0; j < 16; ++j) {
            int tj = t0 + 4 * j;
            if (tj > Tn - 4) tj = Tn - 4;
            rx[j] = *(const float4*)&xr[tj];
        }
        {
            int t1 = t0 + as, t2 = t1 + 32;
            float a1 = 0.f, a2 = 0.f;
            if (t1 < thi) { float df = lr - nb[t1]; a1 = __expf(fmaf(-5.f * df, df, -ml)) * il; }
            if (t2 < thi) { float df = lr - nb[t2]; a2 = __expf(fmaf(-5.f * df, df, -ml)) * il; }
            sA[as][al] = a1;
            sA[as + 32][al] = a2;
            if (dh == 0) {
                if (t1 < thi) ar[t1] = a1;
                if (t2 < thi) ar[t2] = a2;
            }
        }
        __syncthreads();
#pragma unroll
        for (int c = 0; c < 16; ++c) {
            float4 xv = rx[c];
#pragma unroll
            for (int e = 0; e < 4; ++e) {
                int s = 4 * c + e;
                float xs = ((const float*)&xv)[e];
                float4 a0 = *(const float4*)&sA[s][0];
                float4 a1 = *(const float4*)&sA[s][4];
                acc[0] = fmaf(xs, a0.x, acc[0]);
                acc[1] = fmaf(xs, a0.y, acc[1]);
                acc[2] = fmaf(xs, a0.z, acc[2]);
                acc[3] = fmaf(xs, a0.w, acc[3]);
                acc[4] = fmaf(xs, a1.x, acc[4]);
                acc[5] = fmaf(xs, a1.y, acc[5]);
                acc[6] = fmaf(xs, a1.z, acc[6]);
                acc[7] = fmaf(xs, a1.w, acc[7]);
            }
        }
        __syncthreads();
    }

    *(float4*)&z[zr]     = make_float4(acc[0], acc[1], acc[2], acc[3]);
    *(float4*)&z[zr + 4] = make_float4(acc[4], acc[5], acc[6], acc[7]);
}

extern "C" void kernel_launch(void* const* d_in, const int* in_sizes, int n_in,
                              void* d_out, int out_size, void* d_ws, size_t ws_size,
                              hipStream_t stream) {
    const float* x    = (const float*)d_in[0];
    const float* w    = (const float*)d_in[1];
    const int*   xlen = (const int*)d_in[3];
    float* out = (float*)d_out;

    const size_t OFF_Z     = 0;
    const size_t OFF_ZMASK = (size_t)Bn * Dn * Ln;
    const size_t OFF_ZLEN  = OFF_ZMASK + (size_t)Bn * Ln;
    const size_t OFF_ALIGN = OFF_ZLEN + Bn;
    const size_t OFF_LOSS  = OFF_ALIGN + (size_t)Bn * Ln * Tn;

    float* score     = (float*)d_ws;
    float* norm      = score + (size_t)Bn * Tn;
    float* loss_part = norm + (size_t)Bn * Tn;
    int*   wlo       = (int*)(loss_part + Bn);
    int*   whi       = wlo + Bn * NLT;
    float* sMw       = (float*)(whi + Bn * NLT);
    float* sIw       = sMw + (size_t)Bn * Ln;

    scorefill_kernel<<<1024 + 4096, 256, 0, stream>>>(x, w, xlen, score,
                                                      out + OFF_ALIGN);
    scan_kernel<<<Bn, 256, 0, stream>>>(score, xlen, norm, loss_part,
                                        out + OFF_ZMASK, out + OFF_ZLEN,
                                        wlo, whi, sMw, sIw);
    z_kernel<<<Bn * NLT * 2, 256, 0, stream>>>(x, norm, xlen, wlo, whi,
                                               sMw, sIw, loss_part,
                                               out + OFF_ALIGN, out + OFF_Z,
                                               out + OFF_LOSS);
}

// Round 17
// 49.944 us; speedup vs baseline: 1.3809x; 1.0574x over previous
//
#include <hip/hip_runtime.h>
#include <cstddef>

#define Bn 16
#define Dn 512
#define Tn 2048
#define Ln 512
#define NLT 64      // l-tiles per b (Ln/8)

// ---- K1: pure score, 1024 blocks (b, 32-t chunk), batch-loaded ----------
__global__ __launch_bounds__(256) void score_kernel(const float* __restrict__ x,
                                                    const float* __restrict__ w,
                                                    const int* __restrict__ xlen,
                                                    float* __restrict__ score) {
    int bid = blockIdx.x;
    int tid = threadIdx.x;
    int b   = bid >> 6;
    int tc  = bid & 63;
    int xl  = xlen[b];
    int t0c = tc * 32;
    if (t0c >= xl) {
        if (tid < 8)
            *(float4*)&score[b * Tn + t0c + tid * 4] = make_float4(0.f, 0.f, 0.f, 0.f);
        return;
    }
    int tq = tid & 7;
    int dg = tid >> 3;
    int t0 = t0c + tq * 4;
    const float* xb = x + (size_t)b * Dn * Tn + (size_t)(dg * 16) * Tn + t0;
    const float* wb = w + dg * 16;

    float4 rx[16];
#pragma unroll
    for (int i = 0; i < 16; ++i)
        rx[i] = *(const float4*)&xb[(size_t)i * Tn];

    float4 acc = make_float4(0.f, 0.f, 0.f, 0.f);
#pragma unroll
    for (int i = 0; i < 16; ++i) {
        float wd = wb[i];
        acc.x = fmaf(rx[i].x, wd, acc.x);
        acc.y = fmaf(rx[i].y, wd, acc.y);
        acc.z = fmaf(rx[i].z, wd, acc.z);
        acc.w = fmaf(rx[i].w, wd, acc.w);
    }

    __shared__ float4 red[32][8];
    __shared__ float4 red2[8][8];
    red[dg][tq] = acc;
    __syncthreads();
    if (tid < 64) {
        int q = tid & 7, g = tid >> 3;
        float4 s0 = red[g * 4 + 0][q], s1 = red[g * 4 + 1][q];
        float4 s2 = red[g * 4 + 2][q], s3 = red[g * 4 + 3][q];
        float4 s;
        s.x = (s0.x + s1.x) + (s2.x + s3.x);
        s.y = (s0.y + s1.y) + (s2.y + s3.y);
        s.z = (s0.z + s1.z) + (s2.z + s3.z);
        s.w = (s0.w + s1.w) + (s2.w + s3.w);
        red2[g][q] = s;
    }
    __syncthreads();
    if (tid < 8) {
        float4 s = red2[0][tid];
#pragma unroll
        for (int g = 1; g < 8; ++g) {
            float4 r = red2[g][tid];
            s.x += r.x; s.y += r.y; s.z += r.z; s.w += r.w;
        }
        int t = t0c + tid * 4;
        float4 o;
        o.x = (t + 0 < xl) ? __expf(s.x) : 0.f;
        o.y = (t + 1 < xl) ? __expf(s.y) : 0.f;
        o.z = (t + 2 < xl) ? __expf(s.z) : 0.f;
        o.w = (t + 3 < xl) ? __expf(s.w) : 0.f;
        *(float4*)&score[b * Tn + t] = o;
    }
}

// -------- K2: 1024-wide scan -> norm, loss, masks, windows, row stats ----
__global__ __launch_bounds__(1024) void scan_kernel(const float* __restrict__ score,
                                                    const int* __restrict__ xlen,
                                                    float* __restrict__ norm,
                                                    float* __restrict__ loss_part,
                                                    float* __restrict__ zmask_out,
                                                    float* __restrict__ zlen_out,
                                                    int* __restrict__ wlo,
                                                    int* __restrict__ whi,
                                                    float* __restrict__ sMout,
                                                    float* __restrict__ sIout) {
    int b = blockIdx.x, tid = threadIdx.x;
    int xl = xlen[b];
    int zl = (xl + 3) >> 2;
    const float* sc = score + b * Tn;

    __shared__ float sNorm[Tn];   // 8 KB
    __shared__ int   sTC[Ln];     // 2 KB
    __shared__ float wsum[16], lw[16];

    float v0 = sc[2 * tid], v1 = sc[2 * tid + 1];
    float s  = v0 + v1;

    float ps = s;
#pragma unroll
    for (int off = 1; off < 64; off <<= 1) {
        float n = __shfl_up(ps, off, 64);
        if ((tid & 63) >= off) ps += n;
    }
    if ((tid & 63) == 63) wsum[tid >> 6] = ps;
    __syncthreads();
    float base = 0.f, total = 0.f;
#pragma unroll
    for (int w2 = 0; w2 < 16; ++w2) {
        float t = wsum[w2];
        if (w2 < (tid >> 6)) base += t;
        total += t;
    }
    float cum0  = sc[0];
    float scale = (float)(zl - 1) / (total - cum0);

    float run = base + ps - s;                 // exclusive prefix
    float n0v = (run + v0 - cum0) * scale;
    float n1v = (run + s  - cum0) * scale;
    norm[b * Tn + 2 * tid]     = n0v;
    norm[b * Tn + 2 * tid + 1] = n1v;
    sNorm[2 * tid]     = n0v;
    sNorm[2 * tid + 1] = n1v;

    float ls = 0.f;
    {
        int t = 2 * tid;
        if (t >= 1 && t < xl) ls += fmaxf(v0 * scale - 1.0f, 0.f);
        if (t + 1 < xl)       ls += fmaxf(v1 * scale - 1.0f, 0.f);
    }
#pragma unroll
    for (int off = 32; off; off >>= 1) ls += __shfl_down(ls, off, 64);
    if ((tid & 63) == 0) lw[tid >> 6] = ls;

    if (tid < Ln) {
        zmask_out[b * Ln + tid] = (tid * 4 < xl) ? 1.f : 0.f;
        sTC[tid] = xl - 1;
    }
    if (tid < NLT) {
        wlo[b * NLT + tid] = xl;
        whi[b * NLT + tid] = xl;
    }
    if (tid == 0) zlen_out[b] = (float)zl;
    __syncthreads();                           // sNorm, sTC, lw ready
    if (tid == 0) {
        float t = 0.f;
        for (int i = 0; i < 16; ++i) t += lw[i];
        loss_part[b] = t / (float)(xl - 1);
    }

    // crossing detection (norm monotone non-decreasing => unique crossings)
#pragma unroll
    for (int k = 0; k < 2; ++k) {
        int t = 2 * tid + k;
        float vv = k ? n1v : n0v;
        float p  = (t == 0) ? -1e9f : sNorm[t - 1];
        int lsr = (int)floorf((p + 1.5f) * 0.125f) + 1; if (lsr < 0) lsr = 0;
        int ler = (int)floorf((vv + 1.5f) * 0.125f);    if (ler > NLT - 1) ler = NLT - 1;
        for (int lt = lsr; lt <= ler; ++lt) wlo[b * NLT + lt] = t;
        int hs = (int)ceilf((p - 8.5f) * 0.125f);       if (hs < 0) hs = 0;
        int he = (int)ceilf((vv - 8.5f) * 0.125f) - 1;  if (he > NLT - 1) he = NLT - 1;
        for (int lt = hs; lt <= he; ++lt) whi[b * NLT + lt] = t;
        int cs = (int)floorf(p) + 1;  if (cs < 0) cs = 0;
        int ce = (int)floorf(vv);     if (ce > Ln - 1) ce = Ln - 1;
        for (int l = cs; l <= ce; ++l) sTC[l] = t;
    }
    __syncthreads();

    // per-row exact max + truncated sum (one row per thread)
    if (tid < Ln) {
        int l = tid;
        float mv = 0.f, iv = 0.f;
        if (l < zl) {
            int tc2 = sTC[l];
            float d1 = (float)l - sNorm[tc2];
            float m  = -5.f * d1 * d1;
            if (tc2 > 0) { float d0v = (float)l - sNorm[tc2 - 1]; float c = -5.f * d0v * d0v; m = fmaxf(m, c); }
            int lo = (l >= 2) ? sTC[l - 2] : 0;
            int hi = (l + 2 <= zl - 1) ? sTC[l + 2] : xl;
            int tcm1 = (tc2 > 0) ? tc2 - 1 : 0;
            if (lo > tcm1) lo = tcm1;
            int tcp1 = (tc2 + 1 < xl) ? tc2 + 1 : xl;
            if (hi < tcp1) hi = tcp1;
            float ssum = 0.f;
            for (int t = lo; t < hi; ++t) {
                float df = (float)l - sNorm[t];
                ssum += __expf(-5.f * df * df - m);
            }
            mv = m; iv = 1.f / ssum;
        }
        sMout[b * Ln + l] = mv;
        sIout[b * Ln + l] = iv;
    }
}

// -------- K3: z GEMM + LIVE align rows + DEAD-row fill (appended blocks) -
__global__ __launch_bounds__(256) void z_kernel(const float* __restrict__ x,
                                                const float* __restrict__ norm,
                                                const int* __restrict__ xlen,
                                                const int* __restrict__ wlo,
                                                const int* __restrict__ whi,
                                                const float* __restrict__ sM,
                                                const float* __restrict__ sI,
                                                const float* __restrict__ loss_part,
                                                float* __restrict__ align,
                                                float* __restrict__ z,
                                                float* __restrict__ out_loss) {
    int tid = threadIdx.x;
    int bid = blockIdx.x;

    if (bid >= 2048) {                         // ---- dead-row fill role ----
        int r0 = (bid - 2048) * 2;             // two align rows per block
        float4 z4 = make_float4(0.f, 0.f, 0.f, 0.f);
#pragma unroll
        for (int rr = 0; rr < 2; ++rr) {
            int r = r0 + rr;
            int b = r >> 9, l = r & 511;
            int zl = (xlen[b] + 3) >> 2;
            if (l < zl) continue;              // live rows: z-role writes them
            float4* row4 = (float4*)(align + (size_t)r * Tn);
            row4[tid]       = z4;
            row4[tid + 256] = z4;
        }
        return;
    }

    if (bid == 0 && tid == 0) {
        float s = 0.f;
        for (int i = 0; i < Bn; ++i) s += loss_part[i];
        out_loss[0] = s / (float)Bn;
    }
    int swz = (bid & 7) * 256 + (bid >> 3);   // bijective: 2048 = 8*256
    int b   = swz >> 7;
    int rem = swz & 127;
    int lt  = rem >> 1;
    int dh  = rem & 1;
    int l0  = lt * 8;
    int xl  = xlen[b];
    int zl  = (xl + 3) >> 2;
    int d   = dh * 256 + tid;
    size_t zr = (size_t)(b * Dn + d) * Ln + l0;

    if (l0 >= zl) {                            // dead tile: fill role zeroes align
        float4 z4 = make_float4(0.f, 0.f, 0.f, 0.f);
        *(float4*)&z[zr] = z4; *(float4*)&z[zr + 4] = z4;
        return;
    }

    int tlo = wlo[b * NLT + lt];
    int thi = whi[b * NLT + lt];
    if (thi > xl) thi = xl;
    int tA = tlo & ~15;                        // 64B-aligned window start

    // ---- outside-window zero-fill for this tile's 8 align rows ----
    {
        int start4 = (thi + 3) & ~3;
        if (start4 > Tn) start4 = Tn;
        int rest   = Tn - start4 - tA;
        if (rest < 0) rest = 0;
        int mid4   = start4 + ((rest >> 3) << 2);
        int row    = tid >> 5, lane32 = tid & 31;
        float* arw = align + (size_t)(b * Ln + l0 + row) * Tn;
        float4 z4f = make_float4(0.f, 0.f, 0.f, 0.f);
        if (dh == 0) {
            for (int q = lane32; q < (tA >> 2); q += 32)
                ((float4*)arw)[q] = z4f;
            if (thi + lane32 < start4) arw[thi + lane32] = 0.f;
            for (int q = (start4 >> 2) + lane32; q < (mid4 >> 2); q += 32)
                ((float4*)arw)[q] = z4f;
        } else {
            for (int q = (mid4 >> 2) + lane32; q < (Tn >> 2); q += 32)
                ((float4*)arw)[q] = z4f;
        }
    }

    __shared__ float sA[64][8];                // 2 KB, A[s][l]
    const float* nb = norm + b * Tn;
    const float* xr = x + (size_t)(b * Dn + d) * Tn;

    int al = tid >> 5;
    int as = tid & 31;
    float ml = sM[b * Ln + l0 + al];
    float il = sI[b * Ln + l0 + al];
    float lr = (float)(l0 + al);
    float* ar = align + (size_t)(b * Ln + l0 + al) * Tn;

    float acc[8] = {};
    float4 rx[16];

    for (int t0 = tA; t0 < thi; t0 += 64) {    // normally ONE iteration
#pragma unroll
        for (int j = 0; j < 16; ++j) {
            int tj = t0 + 4 * j;
            if (tj > Tn - 4) tj = Tn - 4;
            rx[j] = *(const float4*)&xr[tj];
        }
        {
            int t1 = t0 + as, t2 = t1 + 32;
            float a1 = 0.f, a2 = 0.f;
            if (t1 < thi) { float df = lr - nb[t1]; a1 = __expf(fmaf(-5.f * df, df, -ml)) * il; }
            if (t2 < thi) { float df = lr - nb[t2]; a2 = __expf(fmaf(-5.f * df, df, -ml)) * il; }
            sA[as][al] = a1;
            sA[as + 32][al] = a2;
            if (dh == 0) {
                if (t1 < thi) ar[t1] = a1;
                if (t2 < thi) ar[t2] = a2;
            }
        }
        __syncthreads();
#pragma unroll
        for (int c = 0; c < 16; ++c) {
            float4 xv = rx[c];
#pragma unroll
            for (int e = 0; e < 4; ++e) {
                int s = 4 * c + e;
                float xs = ((const float*)&xv)[e];
                float4 a0 = *(const float4*)&sA[s][0];
                float4 a1 = *(const float4*)&sA[s][4];
                acc[0] = fmaf(xs, a0.x, acc[0]);
                acc[1] = fmaf(xs, a0.y, acc[1]);
                acc[2] = fmaf(xs, a0.z, acc[2]);
                acc[3] = fmaf(xs, a0.w, acc[3]);
                acc[4] = fmaf(xs, a1.x, acc[4]);
                acc[5] = fmaf(xs, a1.y, acc[5]);
                acc[6] = fmaf(xs, a1.z, acc[6]);
                acc[7] = fmaf(xs, a1.w, acc[7]);
            }
        }
        __syncthreads();
    }

    *(float4*)&z[zr]     = make_float4(acc[0], acc[1], acc[2], acc[3]);
    *(float4*)&z[zr + 4] = make_float4(acc[4], acc[5], acc[6], acc[7]);
}

extern "C" void kernel_launch(void* const* d_in, const int* in_sizes, int n_in,
                              void* d_out, int out_size, void* d_ws, size_t ws_size,
                              hipStream_t stream) {
    const float* x    = (const float*)d_in[0];
    const float* w    = (const float*)d_in[1];
    const int*   xlen = (const int*)d_in[3];
    float* out = (float*)d_out;

    const size_t OFF_Z     = 0;
    const size_t OFF_ZMASK = (size_t)Bn * Dn * Ln;
    const size_t OFF_ZLEN  = OFF_ZMASK + (size_t)Bn * Ln;
    const size_t OFF_ALIGN = OFF_ZLEN + Bn;
    const size_t OFF_LOSS  = OFF_ALIGN + (size_t)Bn * Ln * Tn;

    float* score     = (float*)d_ws;
    float* norm      = score + (size_t)Bn * Tn;
    float* loss_part = norm + (size_t)Bn * Tn;
    int*   wlo       = (int*)(loss_part + Bn);
    int*   whi       = wlo + Bn * NLT;
    float* sMw       = (float*)(whi + Bn * NLT);
    float* sIw       = sMw + (size_t)Bn * Ln;

    score_kernel<<<1024, 256, 0, stream>>>(x, w, xlen, score);
    scan_kernel<<<Bn, 1024, 0, stream>>>(score, xlen, norm, loss_part,
                                         out + OFF_ZMASK, out + OFF_ZLEN,
                                         wlo, whi, sMw, sIw);
    z_kernel<<<2048 + 4096, 256, 0, stream>>>(x, norm, xlen, wlo, whi,
                                              sMw, sIw, loss_part,
                                              out + OFF_ALIGN, out + OFF_Z,
                                              out + OFF_LOSS);
}